// Round 11
// baseline (359.014 us; speedup 1.0000x reference)
//
#include <hip/hip_runtime.h>
#include <hip/hip_bf16.h>

typedef __attribute__((ext_vector_type(8))) short bf16x8;
typedef __attribute__((ext_vector_type(4))) short bf16x4;
typedef __attribute__((ext_vector_type(4))) float f32x4;

#define MFMA16(a, b, c) __builtin_amdgcn_mfma_f32_16x16x32_bf16((a), (b), (c), 0, 0, 0)

__device__ __forceinline__ f32x4 mfma_k16(bf16x4 a, bf16x4 b, f32x4 c) {
#if __has_builtin(__builtin_amdgcn_mfma_f32_16x16x16bf16_1k)
  return __builtin_amdgcn_mfma_f32_16x16x16bf16_1k(a, b, c, 0, 0, 0);
#elif __has_builtin(__builtin_amdgcn_mfma_f32_16x16x16_bf16)
  return __builtin_amdgcn_mfma_f32_16x16x16_bf16(a, b, c, 0, 0, 0);
#else
  asm("v_mfma_f32_16x16x16_bf16 %0, %1, %2, %0" : "+v"(c) : "v"(a), "v"(b));
  return c;
#endif
}

__device__ __forceinline__ ushort f2bf(float f) {
  union { __hip_bfloat16 h; ushort u; } cv;
  cv.h = __float2bfloat16(f);
  return cv.u;
}

__device__ __forceinline__ float bf2f(ushort u) {
  union { float f; unsigned int i; } c;
  c.i = ((unsigned int)u) << 16;
  return c.f;
}

__device__ __forceinline__ void gload16(const void* g, void* l) {
  __builtin_amdgcn_global_load_lds((const __attribute__((address_space(1))) void*)g,
                                   (__attribute__((address_space(3))) void*)l, 16, 0, 0);
}

// ---------------- merged weight transpose+cast: all 6 matrices ----------------
__global__ void wtrans_all(const float* __restrict__ wq, const float* __restrict__ wk,
                           const float* __restrict__ wv, const float* __restrict__ wo,
                           const float* __restrict__ w1, const float* __restrict__ w2,
                           ushort* __restrict__ wqT, ushort* __restrict__ wkT,
                           ushort* __restrict__ wvT, ushort* __restrict__ woT,
                           ushort* __restrict__ w1T, ushort* __restrict__ w2T) {
  __shared__ float t[32][33];
  int id = blockIdx.x;
  const float* W;
  ushort* Wt;
  int K, N, nbx;
  if (id < 2304) {  // 4 square 768x768 matrices, 576 tiles each
    const int m = id / 576;
    id -= m * 576;
    W = (m == 0) ? wq : (m == 1) ? wk : (m == 2) ? wv : wo;
    Wt = (m == 0) ? wqT : (m == 1) ? wkT : (m == 2) ? wvT : woT;
    K = 768; N = 768; nbx = 24;
  } else if (id < 4608) {
    id -= 2304; W = w1; Wt = w1T; K = 768; N = 3072; nbx = 96;
  } else {
    id -= 4608; W = w2; Wt = w2T; K = 3072; N = 768; nbx = 24;
  }
  const int nb = (id % nbx) * 32, kb = (id / nbx) * 32;
  const int tx = threadIdx.x & 31, ty = threadIdx.x >> 5;
#pragma unroll
  for (int i = 0; i < 4; ++i)
    t[ty + i * 8][tx] = W[(size_t)(kb + ty + i * 8) * N + nb + tx];
  __syncthreads();
#pragma unroll
  for (int i = 0; i < 4; ++i)
    Wt[(size_t)(nb + ty + i * 8) * K + kb + tx] = f2bf(t[tx][ty + i * 8]);
}

// ---------------- RMSNorm fp32 row(768) -> bf16 (192 thr, float4) ------------
__global__ void rmsnorm_kernel(const float* __restrict__ x, const float* __restrict__ g,
                               ushort* __restrict__ out) {
  const int row = blockIdx.x, t = threadIdx.x;
  const float4 v = *(const float4*)(x + (size_t)row * 768 + 4 * t);
  float ss = v.x * v.x + v.y * v.y + v.z * v.z + v.w * v.w;
#pragma unroll
  for (int off = 1; off < 64; off <<= 1) ss += __shfl_xor(ss, off);
  __shared__ float part[3];
  if ((t & 63) == 0) part[t >> 6] = ss;
  __syncthreads();
  const float tot = part[0] + part[1] + part[2];
  const float r = rsqrtf(tot * (1.0f / 768.0f) + 1e-6f);
  const float4 gg = *(const float4*)(g + 4 * t);
  ushort4 o;
  o.x = f2bf(v.x * r * gg.x);
  o.y = f2bf(v.y * r * gg.y);
  o.z = f2bf(v.z * r * gg.z);
  o.w = f2bf(v.w * r * gg.w);
  *(ushort4*)(out + (size_t)row * 768 + 4 * t) = o;
}

// ------ 128^2 GEMM: C = A*Bt^T, 2-phase counted vmcnt (for N=768 GEMMs) ------
enum { EPI_BF16 = 0, EPI_VT = 1, EPI_RESID = 2, EPI_BIAS_GELU = 3, EPI_BIAS_RESID = 4 };

template <int EPI>
__global__ __launch_bounds__(256) void gemm_bt(
    const ushort* __restrict__ A, const ushort* __restrict__ Bt, void* __restrict__ Cout,
    const float* __restrict__ bias, const float* __restrict__ resid, int M, int N, int K,
    float scale) {
  __shared__ ushort As[2][128 * 64];
  __shared__ ushort Bs[2][128 * 64];
  const int tid = threadIdx.x;
  const int lane = tid & 63, wid = tid >> 6;
  const int wm = wid >> 1, wn = wid & 1;
  const int l15 = lane & 15, l4 = lane >> 4;
  const int m0 = blockIdx.y * 128, n0 = blockIdx.x * 128;
  const int srow = lane >> 3, sslot = lane & 7;
  const int skel = (sslot ^ srow) << 3;  // pre-swizzled source k offset

  f32x4 acc[4][4] = {};

#pragma unroll
  for (int i = 0; i < 4; ++i) {
    const int c = i * 4 + wid;
    const int row = c * 8 + srow;
    gload16(A + (size_t)(m0 + row) * K + skel, (char*)As[0] + c * 1024);
    gload16(Bt + (size_t)(n0 + row) * K + skel, (char*)Bs[0] + c * 1024);
  }

  int cur = 0;
  for (int k0 = 0; k0 < K; k0 += 64) {
    if (k0 + 64 < K) {
      char* dA = (char*)As[cur ^ 1];
      char* dB = (char*)Bs[cur ^ 1];
#pragma unroll
      for (int i = 0; i < 4; ++i) {
        const int c = i * 4 + wid;
        const int row = c * 8 + srow;
        gload16(A + (size_t)(m0 + row) * K + k0 + 64 + skel, dA + c * 1024);
        gload16(Bt + (size_t)(n0 + row) * K + k0 + 64 + skel, dB + c * 1024);
      }
      asm volatile("s_waitcnt vmcnt(8)" ::: "memory");
    } else {
      asm volatile("s_waitcnt vmcnt(0)" ::: "memory");
    }
    __builtin_amdgcn_s_barrier();

    const char* pA = (const char*)As[cur];
    const char* pB = (const char*)Bs[cur];
#pragma unroll
    for (int ks = 0; ks < 2; ++ks) {
      bf16x8 af[4], bfr[4];
#pragma unroll
      for (int mi = 0; mi < 4; ++mi) {
        const int row = wm * 64 + mi * 16 + l15;
        const int slot = (ks * 4 + l4) ^ (row & 7);
        af[mi] = *(const bf16x8*)(pA + row * 128 + slot * 16);
      }
#pragma unroll
      for (int ni = 0; ni < 4; ++ni) {
        const int row = wn * 64 + ni * 16 + l15;
        const int slot = (ks * 4 + l4) ^ (row & 7);
        bfr[ni] = *(const bf16x8*)(pB + row * 128 + slot * 16);
      }
#pragma unroll
      for (int mi = 0; mi < 4; ++mi)
#pragma unroll
        for (int ni = 0; ni < 4; ++ni)
          acc[mi][ni] = MFMA16(af[mi], bfr[ni], acc[mi][ni]);
    }
    asm volatile("" ::: "memory");
    __builtin_amdgcn_s_barrier();
    cur ^= 1;
  }

#pragma unroll
  for (int mi = 0; mi < 4; ++mi) {
#pragma unroll
    for (int ni = 0; ni < 4; ++ni) {
      const int gm = m0 + wm * 64 + mi * 16 + l4 * 4;
      const int gn = n0 + wn * 64 + ni * 16 + l15;
      f32x4 v = acc[mi][ni];
#pragma unroll
      for (int r = 0; r < 4; ++r) {
        const size_t idx = (size_t)(gm + r) * N + gn;
        const float f = v[r];
        if constexpr (EPI == EPI_BF16) {
          ((ushort*)Cout)[idx] = f2bf(f * scale);
        } else if constexpr (EPI == EPI_RESID) {
          ((float*)Cout)[idx] = f + resid[idx];
        } else if constexpr (EPI == EPI_BIAS_GELU) {
          const float u = f + bias[gn];
          const float gl = 0.5f * u * (1.0f + erff(u * 0.70710678118654752f));
          ((ushort*)Cout)[idx] = f2bf(gl);
        } else if constexpr (EPI == EPI_BIAS_RESID) {
          ((float*)Cout)[idx] = f + bias[gn] + resid[idx];
        }
      }
    }
  }
}

// ===== 256x256 8-wave 8-phase GEMM core (BK=64 split into 2 k-halves) ========
// LDS per operand: [2 buf][2 kh][256 rows][32 k] bf16 = 64KB (A) + 64KB (B).
// Phase p: 8 ds_read_b128 (conflict-free: contiguous 1KB/frag-read) ->
//   stage one half-tile (2 gload_lds) -> s_barrier -> setprio(1) -> 16 MFMA ->
//   setprio(0) -> [vmcnt(8) on even phases] -> s_barrier.
// Stage targets are written only in phases after their last reader (race-free);
// counted vmcnt keeps ~8-16 loads in flight across barriers (never drains).
#define G256_VM8 asm volatile("s_waitcnt vmcnt(8)" ::: "memory")
#define G256_VM4 asm volatile("s_waitcnt vmcnt(4)" ::: "memory")
#define G256_VM0 asm volatile("s_waitcnt vmcnt(0)" ::: "memory")
#define G256_NOP (void)0

#define G256_PHASE(BUF, KH, MH, STAGE, TAILW)                                  \
  {                                                                            \
    asm volatile("" ::: "memory");                                             \
    const char* Ab_ = AsB + (BUF) * 32768 + (KH) * 16384 + aro;                \
    const char* Bb_ = BsB + (BUF) * 32768 + (KH) * 16384 + bro;                \
    bf16x8 af_[4], bf_[4];                                                     \
    _Pragma("unroll") for (int i_ = 0; i_ < 4; ++i_)                           \
        af_[i_] = *(const bf16x8*)(Ab_ + (MH) * 4096 + i_ * 1024);             \
    _Pragma("unroll") for (int i_ = 0; i_ < 4; ++i_)                           \
        bf_[i_] = *(const bf16x8*)(Bb_ + i_ * 1024);                           \
    STAGE;                                                                     \
    __builtin_amdgcn_s_barrier();                                              \
    __builtin_amdgcn_s_setprio(1);                                             \
    _Pragma("unroll") for (int i_ = 0; i_ < 4; ++i_)                           \
        _Pragma("unroll") for (int n_ = 0; n_ < 4; ++n_)                       \
            acc[(MH) * 4 + i_][n_] =                                           \
                MFMA16(af_[i_], bf_[n_], acc[(MH) * 4 + i_][n_]);              \
    __builtin_amdgcn_s_setprio(0);                                             \
    TAILW;                                                                     \
    asm volatile("" ::: "memory");                                             \
    __builtin_amdgcn_s_barrier();                                              \
  }

__device__ __forceinline__ void gemm256_core(const ushort* __restrict__ A,
                                             const ushort* __restrict__ Bt, int K,
                                             int m0, int n0, char* AsB, char* BsB,
                                             f32x4 (&acc)[8][4]) {
  const int tid = threadIdx.x, lane = tid & 63, wid = tid >> 6;
  const int l15 = lane & 15, l4 = lane >> 4;
  const int wm = wid >> 2, wn = wid & 3;
  const int aro = (wm * 128 + l15) * 64 + l4 * 16;  // A frag base byte offset
  const int bro = (wn * 64 + l15) * 64 + l4 * 16;   // B frag base byte offset

  // staging source pointers: rows (tid>>2)+{0,128}, k-slot (tid&3)*8
  const ushort* pA0 = A + (size_t)(m0 + (tid >> 2)) * K + ((tid & 3) << 3);
  const ushort* pB0 = Bt + (size_t)(n0 + (tid >> 2)) * K + ((tid & 3) << 3);
  const int wofs = wid << 10;

  auto stA = [&](int kt, int kh, int buf) {
    const ushort* s = pA0 + kt * 64 + kh * 32;
    char* d = AsB + buf * 32768 + kh * 16384 + wofs;
    gload16(s, d);
    gload16(s + (size_t)128 * K, d + 8192);
  };
  auto stB = [&](int kt, int kh, int buf) {
    const ushort* s = pB0 + kt * 64 + kh * 32;
    char* d = BsB + buf * 32768 + kh * 16384 + wofs;
    gload16(s, d);
    gload16(s + (size_t)128 * K, d + 8192);
  };

  // prologue: T0 fully, T1 kh0
  stA(0, 0, 0); stB(0, 0, 0);
  stA(0, 1, 0); stB(0, 1, 0);
  stA(1, 0, 1); stB(1, 0, 1);
  G256_VM8;  // T0.kh0 landed (8 newer loads outstanding)
  __builtin_amdgcn_s_barrier();

  const int niter = K >> 7;  // K/128, >= 2
  for (int j = 0; j < niter - 1; ++j) {
    const int t1 = 2 * j + 1, t2 = 2 * j + 2, t3 = 2 * j + 3;
    G256_PHASE(0, 0, 0, stA(t1, 1, 1), G256_NOP)  // ph1
    G256_PHASE(0, 0, 1, stB(t1, 1, 1), G256_VM8)  // ph2
    G256_PHASE(0, 1, 0, stA(t2, 0, 0), G256_NOP)  // ph3
    G256_PHASE(0, 1, 1, stB(t2, 0, 0), G256_VM8)  // ph4
    G256_PHASE(1, 0, 0, stA(t2, 1, 0), G256_NOP)  // ph5
    G256_PHASE(1, 0, 1, stB(t2, 1, 0), G256_VM8)  // ph6
    G256_PHASE(1, 1, 0, stA(t3, 0, 1), G256_NOP)  // ph7
    G256_PHASE(1, 1, 1, stB(t3, 0, 1), G256_VM8)  // ph8
  }
  {  // peeled final iteration (no further staging; exact smaller vmcnt counts)
    const int t1 = (K >> 6) - 1;
    G256_PHASE(0, 0, 0, stA(t1, 1, 1), G256_NOP)
    G256_PHASE(0, 0, 1, stB(t1, 1, 1), G256_VM8)
    G256_PHASE(0, 1, 0, G256_NOP, G256_NOP)
    G256_PHASE(0, 1, 1, G256_NOP, G256_VM4)
    G256_PHASE(1, 0, 0, G256_NOP, G256_NOP)
    G256_PHASE(1, 0, 1, G256_NOP, G256_VM0)
    G256_PHASE(1, 1, 0, G256_NOP, G256_NOP)
    G256_PHASE(1, 1, 1, G256_NOP, G256_NOP)
  }
}

// ---- 256^2 8-phase FFN1: C = gelu(A*Bt^T + bias) -> bf16 --------------------
__global__ __launch_bounds__(512, 2) void gemm256_gelu(
    const ushort* __restrict__ A, const ushort* __restrict__ Bt,
    ushort* __restrict__ Cout, const float* __restrict__ bias, int N, int K) {
  __shared__ char AsB[65536];
  __shared__ char BsB[65536];
  const int tid = threadIdx.x, lane = tid & 63, wid = tid >> 6;
  const int l15 = lane & 15, l4 = lane >> 4;
  const int wm = wid >> 2, wn = wid & 3;
  const int m0 = blockIdx.y * 256, n0 = blockIdx.x * 256;

  f32x4 acc[8][4] = {};
  gemm256_core(A, Bt, K, m0, n0, AsB, BsB, acc);

#pragma unroll
  for (int mi = 0; mi < 8; ++mi) {
#pragma unroll
    for (int ni = 0; ni < 4; ++ni) {
      const int gm = m0 + wm * 128 + mi * 16 + l4 * 4;
      const int gn = n0 + wn * 64 + ni * 16 + l15;
      const float bv = bias[gn];
      f32x4 v = acc[mi][ni];
#pragma unroll
      for (int r = 0; r < 4; ++r) {
        const float u = v[r] + bv;
        const float gl = 0.5f * u * (1.0f + erff(u * 0.70710678118654752f));
        Cout[(size_t)(gm + r) * N + gn] = f2bf(gl);
      }
    }
  }
}

// ---- 256^2 8-phase merged QKV GEMM: N=2304, segment epilogue ----------------
__global__ __launch_bounds__(512, 2) void gemm256_qkv(
    const ushort* __restrict__ A, const ushort* __restrict__ Bt,
    ushort* __restrict__ qout, ushort* __restrict__ kout, ushort* __restrict__ vtout,
    int K, float qscale) {
  __shared__ char AsB[65536];
  __shared__ char BsB[65536];
  const int tid = threadIdx.x, lane = tid & 63, wid = tid >> 6;
  const int l15 = lane & 15, l4 = lane >> 4;
  const int wm = wid >> 2, wn = wid & 3;
  const int m0 = blockIdx.y * 256, n0 = blockIdx.x * 256;

  f32x4 acc[8][4] = {};
  gemm256_core(A, Bt, K, m0, n0, AsB, BsB, acc);

  const int seg = n0 / 768;  // uniform per block (768 = 3*256)
#pragma unroll
  for (int mi = 0; mi < 8; ++mi) {
#pragma unroll
    for (int ni = 0; ni < 4; ++ni) {
      const int gm = m0 + wm * 128 + mi * 16 + l4 * 4;
      const int gn = n0 + wn * 64 + ni * 16 + l15;
      const int col = gn - seg * 768;
      f32x4 v = acc[mi][ni];
      if (seg == 0) {
#pragma unroll
        for (int r = 0; r < 4; ++r)
          qout[(size_t)(gm + r) * 768 + col] = f2bf(v[r] * qscale);
      } else if (seg == 1) {
#pragma unroll
        for (int r = 0; r < 4; ++r)
          kout[(size_t)(gm + r) * 768 + col] = f2bf(v[r]);
      } else {
        const int b = gm >> 12, tt = gm & 4095;
        const int h = col >> 6, dh = col & 63;
        ushort4 pk;
        pk.x = f2bf(v[0]); pk.y = f2bf(v[1]); pk.z = f2bf(v[2]); pk.w = f2bf(v[3]);
        *(ushort4*)(vtout + (((size_t)(b * 12 + h) * 64 + dh) * 4096 + tt)) = pk;
      }
    }
  }
}

// -------- causal MFMA flash attention, split-K x2 (balance the triangle) ------
__global__ __launch_bounds__(256, 5) void flash_attn_kernel(
    const ushort* __restrict__ Q, const ushort* __restrict__ Kb,
    const ushort* __restrict__ Vt, ushort* __restrict__ Opart,
    float* __restrict__ dsb) {
  __shared__ ushort Ks[2][64 * 64];   // [key][kd], 8-slot XOR swizzle
  __shared__ ushort Vts[2][64 * 64];  // [dh][key], 8-slot XOR swizzle
  const int tid = threadIdx.x, lane = tid & 63, wid = tid >> 6;
  const int l15 = lane & 15, l4 = lane >> 4;
  const int l7 = l15 & 7;
  const int bid = (int)blockIdx.x;
  const int idx = (bid & 7) * 384 + (bid >> 3);
  const int pair = idx >> 1, half = idx & 1;
  const int bh = pair >> 6, b = bh / 12, h = bh % 12;
  const int qb = 63 - (pair & 63);
  const int qbase = qb * 64;
  const int q0 = qbase + wid * 16;
  const int nt = qb + 1;
  const int h0 = nt >> 1;
  const int kt0 = half ? h0 : 0;
  const int kt1 = half ? nt : h0;

  bf16x8 qf0, qf1;
  {
    const ushort* qp = Q + ((size_t)(b * 4096 + q0 + l15) * 768 + h * 64 + l4 * 8);
    qf0 = *(const bf16x8*)qp;
    qf1 = *(const bf16x8*)(qp + 32);
  }
  f32x4 oo[4] = {};
  float dsum = 0.f;

  const int srow_l = lane >> 3;
  const int sco = ((lane & 7) ^ srow_l) << 3;
  const ushort* Kbase = Kb + (size_t)b * 4096 * 768 + h * 64;
  const ushort* Vbase = Vt + (size_t)bh * 64 * 4096;
  const int c0 = wid, c1 = 4 + wid;
  const ushort* kp0 = Kbase + (size_t)(kt0 * 64 + c0 * 8 + srow_l) * 768 + sco;
  const ushort* kp1 = Kbase + (size_t)(kt0 * 64 + c1 * 8 + srow_l) * 768 + sco;
  const ushort* vp0 = Vbase + (size_t)(c0 * 8 + srow_l) * 4096 + kt0 * 64 + sco;
  const ushort* vp1 = Vbase + (size_t)(c1 * 8 + srow_l) * 4096 + kt0 * 64 + sco;

  const int koff0 = l15 * 128 + ((l4 ^ l7) << 4);
  const int koff1 = l15 * 128 + (((4 + l4) ^ l7) << 4);
  const int vbase_off = l15 * 128 + ((l4 & 1) << 3);
  const int t2b = l4 >> 1;

  if (kt0 < kt1) {
    gload16(kp0, (char*)Ks + c0 * 1024);
    gload16(kp1, (char*)Ks + c1 * 1024);
    gload16(vp0, (char*)Vts + c0 * 1024);
    gload16(vp1, (char*)Vts + c1 * 1024);
  }

  int cur = 0;
  for (int kt = kt0; kt < kt1; ++kt) {
    const int k0 = kt << 6;
    if (kt + 1 < kt1) {
      kp0 += 64 * 768; kp1 += 64 * 768;
      vp0 += 64; vp1 += 64;
      const int nb = (cur ^ 1) * 8192;
      gload16(kp0, (char*)Ks + nb + c0 * 1024);
      gload16(kp1, (char*)Ks + nb + c1 * 1024);
      gload16(vp0, (char*)Vts + nb + c0 * 1024);
      gload16(vp1, (char*)Vts + nb + c1 * 1024);
      asm volatile("s_waitcnt vmcnt(4)" ::: "memory");
    } else {
      asm volatile("s_waitcnt vmcnt(0)" ::: "memory");
    }
    __builtin_amdgcn_s_barrier();

    const int nf = (q0 + 16 - k0) >> 4;
    const int nct = nf < 4 ? nf : 4;
    const bool has_diag = (nf <= 4);
    const char* Kc = (const char*)Ks + cur * 8192;
    const char* Vc = (const char*)Vts + cur * 8192;

    __builtin_amdgcn_s_setprio(1);
#pragma unroll
    for (int ct = 0; ct < 4; ++ct) {
      if (ct < nct) {
        f32x4 s = {0.f, 0.f, 0.f, 0.f};
        const bf16x8 kf0 = *(const bf16x8*)(Kc + ct * 2048 + koff0);
        const bf16x8 kf1 = *(const bf16x8*)(Kc + ct * 2048 + koff1);
        s = MFMA16(kf0, qf0, s);
        s = MFMA16(kf1, qf1, s);
        if (has_diag && ct == nct - 1) {
#pragma unroll
          for (int r = 0; r < 4; ++r)
            if (l4 * 4 + r > l15) s[r] = -30.f;
        }
        const float p0 = __builtin_amdgcn_exp2f(s[0]);
        const float p1 = __builtin_amdgcn_exp2f(s[1]);
        const float p2 = __builtin_amdgcn_exp2f(s[2]);
        const float p3 = __builtin_amdgcn_exp2f(s[3]);
        dsum += (p0 + p1) + (p2 + p3);
        union { bf16x4 v; ushort u[4]; } pk;
        pk.u[0] = f2bf(p0); pk.u[1] = f2bf(p1);
        pk.u[2] = f2bf(p2); pk.u[3] = f2bf(p3);
        const int xo = ((2 * ct + t2b) ^ l7) << 4;
#pragma unroll
        for (int dt = 0; dt < 4; ++dt) {
          const bf16x4 vf = *(const bf16x4*)(Vc + dt * 2048 + vbase_off + xo);
          oo[dt] = mfma_k16(pk.v, vf, oo[dt]);
        }
      }
    }
    __builtin_amdgcn_s_setprio(0);
    asm volatile("" ::: "memory");
    __builtin_amdgcn_s_barrier();
    cur ^= 1;
  }

  dsum += __shfl_xor(dsum, 16);
  dsum += __shfl_xor(dsum, 32);
  if (l4 == 0)
    dsb[((half * 24 + b * 12 + h) << 12) + q0 + l15] = dsum;
  ushort* op = Opart + ((size_t)(half * 8192 + b * 4096 + q0 + l4 * 4)) * 768 + h * 64;
#pragma unroll
  for (int r = 0; r < 4; ++r) {
#pragma unroll
    for (int dt = 0; dt < 4; ++dt)
      op[(size_t)r * 768 + dt * 16 + l15] = f2bf(oo[dt][r]);
  }
}

// ---------------- merge split-K partials: attn = (P0+P1)/(d0+d1) -------------
__global__ void attn_merge(const ushort* __restrict__ P, const float* __restrict__ ds,
                           ushort* __restrict__ attn) {
  const int row = blockIdx.x, t = threadIdx.x;
  const int b = row >> 12, tr = row & 4095;
  __shared__ float inv[12];
  if (t < 12) {
    const float d0 = ds[((b * 12 + t) << 12) + tr];
    const float d1 = ds[((24 + b * 12 + t) << 12) + tr];
    inv[t] = 1.0f / (d0 + d1);
  }
  __syncthreads();
  const size_t o0 = (size_t)row * 768 + 4 * t;
  const ushort4 a = *(const ushort4*)(P + o0);
  const ushort4 c = *(const ushort4*)(P + (size_t)8192 * 768 + o0);
  const float iv = inv[t >> 4];
  ushort4 o;
  o.x = f2bf((bf2f(a.x) + bf2f(c.x)) * iv);
  o.y = f2bf((bf2f(a.y) + bf2f(c.y)) * iv);
  o.z = f2bf((bf2f(a.z) + bf2f(c.z)) * iv);
  o.w = f2bf((bf2f(a.w) + bf2f(c.w)) * iv);
  *(ushort4*)(attn + o0) = o;
}

extern "C" void kernel_launch(void* const* d_in, const int* in_sizes, int n_in,
                              void* d_out, int out_size, void* d_ws, size_t ws_size,
                              hipStream_t stream) {
  const float* x  = (const float*)d_in[0];
  const float* wq = (const float*)d_in[1];
  const float* wk = (const float*)d_in[2];
  const float* wv = (const float*)d_in[3];
  const float* wo = (const float*)d_in[4];
  const float* w1 = (const float*)d_in[5];
  const float* b1 = (const float*)d_in[6];
  const float* w2 = (const float*)d_in[7];
  const float* b2 = (const float*)d_in[8];
  const float* g1 = (const float*)d_in[9];
  const float* g2 = (const float*)d_in[10];
  float* out = (float*)d_out;

  char* p = (char*)d_ws;
  ushort* wqT = (ushort*)p; p += (size_t)768 * 768 * 2;   // } contiguous: one
  ushort* wkT = (ushort*)p; p += (size_t)768 * 768 * 2;   // } 2304x768 B matrix
  ushort* wvT = (ushort*)p; p += (size_t)768 * 768 * 2;   // } for merged QKV
  ushort* woT = (ushort*)p; p += (size_t)768 * 768 * 2;
  ushort* w1T = (ushort*)p; p += (size_t)3072 * 768 * 2;
  ushort* w2T = (ushort*)p; p += (size_t)768 * 3072 * 2;
  ushort* xn  = (ushort*)p; p += (size_t)8192 * 768 * 2;
  ushort* qb  = (ushort*)p; p += (size_t)8192 * 768 * 2;
  ushort* kb  = (ushort*)p; p += (size_t)8192 * 768 * 2;
  ushort* vtb = (ushort*)p; p += (size_t)8192 * 768 * 2;
  ushort* attn = (ushort*)p; p += (size_t)8192 * 768 * 2;
  float* x2 = (float*)p; p += (size_t)8192 * 768 * 4;
  float* dsb = (float*)p; p += (size_t)2 * 24 * 4096 * 4;
  ushort* hf = qb;              // reuse qb..attn region (8192*3072*2 bytes)
  ushort* Opart = (ushort*)x2;  // x2 region free until WO GEMM

  const float qscale = 0.125f * 1.44269504088896340736f;

  dim3 blk(256);
  wtrans_all<<<dim3(6912), blk, 0, stream>>>(wq, wk, wv, wo, w1, w2,
                                             wqT, wkT, wvT, woT, w1T, w2T);

  rmsnorm_kernel<<<8192, dim3(192), 0, stream>>>(x, g1, xn);

  gemm256_qkv<<<dim3(9, 32), dim3(512), 0, stream>>>(xn, wqT, qb, kb, vtb, 768, qscale);

  flash_attn_kernel<<<dim3(3072), blk, 0, stream>>>(qb, kb, vtb, Opart, dsb);

  attn_merge<<<dim3(8192), dim3(192), 0, stream>>>(Opart, dsb, attn);

  gemm_bt<EPI_RESID><<<dim3(6, 64), blk, 0, stream>>>(attn, woT, x2, nullptr, x, 8192, 768, 768, 1.0f);

  rmsnorm_kernel<<<8192, dim3(192), 0, stream>>>(x2, g2, xn);

  gemm256_gelu<<<dim3(12, 32), dim3(512), 0, stream>>>(xn, w1T, hf, b1, 3072, 768);

  gemm_bt<EPI_BIAS_RESID><<<dim3(6, 64), blk, 0, stream>>>(hf, w2T, out, b2, x2, 8192, 768, 3072, 1.0f);
}

// Round 13
// 328.301 us; speedup vs baseline: 1.0936x; 1.0936x over previous
//
#include <hip/hip_runtime.h>
#include <hip/hip_bf16.h>

typedef __attribute__((ext_vector_type(8))) short bf16x8;
typedef __attribute__((ext_vector_type(4))) short bf16x4;
typedef __attribute__((ext_vector_type(4))) float f32x4;

#define MFMA16(a, b, c) __builtin_amdgcn_mfma_f32_16x16x32_bf16((a), (b), (c), 0, 0, 0)

__device__ __forceinline__ f32x4 mfma_k16(bf16x4 a, bf16x4 b, f32x4 c) {
#if __has_builtin(__builtin_amdgcn_mfma_f32_16x16x16bf16_1k)
  return __builtin_amdgcn_mfma_f32_16x16x16bf16_1k(a, b, c, 0, 0, 0);
#elif __has_builtin(__builtin_amdgcn_mfma_f32_16x16x16_bf16)
  return __builtin_amdgcn_mfma_f32_16x16x16_bf16(a, b, c, 0, 0, 0);
#else
  asm("v_mfma_f32_16x16x16_bf16 %0, %1, %2, %0" : "+v"(c) : "v"(a), "v"(b));
  return c;
#endif
}

__device__ __forceinline__ ushort f2bf(float f) {
  union { __hip_bfloat16 h; ushort u; } cv;
  cv.h = __float2bfloat16(f);
  return cv.u;
}

__device__ __forceinline__ float bf2f(ushort u) {
  union { float f; unsigned int i; } c;
  c.i = ((unsigned int)u) << 16;
  return c.f;
}

__device__ __forceinline__ void gload16(const void* g, void* l) {
  __builtin_amdgcn_global_load_lds((const __attribute__((address_space(1))) void*)g,
                                   (__attribute__((address_space(3))) void*)l, 16, 0, 0);
}

// ---------------- merged weight transpose+cast: all 6 matrices ----------------
__global__ void wtrans_all(const float* __restrict__ wq, const float* __restrict__ wk,
                           const float* __restrict__ wv, const float* __restrict__ wo,
                           const float* __restrict__ w1, const float* __restrict__ w2,
                           ushort* __restrict__ wqT, ushort* __restrict__ wkT,
                           ushort* __restrict__ wvT, ushort* __restrict__ woT,
                           ushort* __restrict__ w1T, ushort* __restrict__ w2T) {
  __shared__ float t[32][33];
  int id = blockIdx.x;
  const float* W;
  ushort* Wt;
  int K, N, nbx;
  if (id < 2304) {  // 4 square 768x768 matrices, 576 tiles each
    const int m = id / 576;
    id -= m * 576;
    W = (m == 0) ? wq : (m == 1) ? wk : (m == 2) ? wv : wo;
    Wt = (m == 0) ? wqT : (m == 1) ? wkT : (m == 2) ? wvT : woT;
    K = 768; N = 768; nbx = 24;
  } else if (id < 4608) {
    id -= 2304; W = w1; Wt = w1T; K = 768; N = 3072; nbx = 96;
  } else {
    id -= 4608; W = w2; Wt = w2T; K = 3072; N = 768; nbx = 24;
  }
  const int nb = (id % nbx) * 32, kb = (id / nbx) * 32;
  const int tx = threadIdx.x & 31, ty = threadIdx.x >> 5;
#pragma unroll
  for (int i = 0; i < 4; ++i)
    t[ty + i * 8][tx] = W[(size_t)(kb + ty + i * 8) * N + nb + tx];
  __syncthreads();
#pragma unroll
  for (int i = 0; i < 4; ++i)
    Wt[(size_t)(nb + ty + i * 8) * K + kb + tx] = f2bf(t[tx][ty + i * 8]);
}

// ---------------- RMSNorm fp32 row(768) -> bf16 (192 thr, float4) ------------
__global__ void rmsnorm_kernel(const float* __restrict__ x, const float* __restrict__ g,
                               ushort* __restrict__ out) {
  const int row = blockIdx.x, t = threadIdx.x;
  const float4 v = *(const float4*)(x + (size_t)row * 768 + 4 * t);
  float ss = v.x * v.x + v.y * v.y + v.z * v.z + v.w * v.w;
#pragma unroll
  for (int off = 1; off < 64; off <<= 1) ss += __shfl_xor(ss, off);
  __shared__ float part[3];
  if ((t & 63) == 0) part[t >> 6] = ss;
  __syncthreads();
  const float tot = part[0] + part[1] + part[2];
  const float r = rsqrtf(tot * (1.0f / 768.0f) + 1e-6f);
  const float4 gg = *(const float4*)(g + 4 * t);
  ushort4 o;
  o.x = f2bf(v.x * r * gg.x);
  o.y = f2bf(v.y * r * gg.y);
  o.z = f2bf(v.z * r * gg.z);
  o.w = f2bf(v.w * r * gg.w);
  *(ushort4*)(out + (size_t)row * 768 + 4 * t) = o;
}

// ------ 128^2 GEMM: C = A*Bt^T, 2-phase counted vmcnt ------
enum { EPI_BF16 = 0, EPI_VT = 1, EPI_RESID = 2, EPI_BIAS_GELU = 3, EPI_BIAS_RESID = 4 };

template <int EPI>
__global__ __launch_bounds__(256) void gemm_bt(
    const ushort* __restrict__ A, const ushort* __restrict__ Bt, void* __restrict__ Cout,
    const float* __restrict__ bias, const float* __restrict__ resid, int M, int N, int K,
    float scale) {
  __shared__ ushort As[2][128 * 64];
  __shared__ ushort Bs[2][128 * 64];
  const int tid = threadIdx.x;
  const int lane = tid & 63, wid = tid >> 6;
  const int wm = wid >> 1, wn = wid & 1;
  const int l15 = lane & 15, l4 = lane >> 4;
  const int m0 = blockIdx.y * 128, n0 = blockIdx.x * 128;
  const int srow = lane >> 3, sslot = lane & 7;
  const int skel = (sslot ^ srow) << 3;  // pre-swizzled source k offset

  f32x4 acc[4][4] = {};

#pragma unroll
  for (int i = 0; i < 4; ++i) {
    const int c = i * 4 + wid;
    const int row = c * 8 + srow;
    gload16(A + (size_t)(m0 + row) * K + skel, (char*)As[0] + c * 1024);
    gload16(Bt + (size_t)(n0 + row) * K + skel, (char*)Bs[0] + c * 1024);
  }

  int cur = 0;
  for (int k0 = 0; k0 < K; k0 += 64) {
    if (k0 + 64 < K) {
      char* dA = (char*)As[cur ^ 1];
      char* dB = (char*)Bs[cur ^ 1];
#pragma unroll
      for (int i = 0; i < 4; ++i) {
        const int c = i * 4 + wid;
        const int row = c * 8 + srow;
        gload16(A + (size_t)(m0 + row) * K + k0 + 64 + skel, dA + c * 1024);
        gload16(Bt + (size_t)(n0 + row) * K + k0 + 64 + skel, dB + c * 1024);
      }
      asm volatile("s_waitcnt vmcnt(8)" ::: "memory");
    } else {
      asm volatile("s_waitcnt vmcnt(0)" ::: "memory");
    }
    __builtin_amdgcn_s_barrier();

    const char* pA = (const char*)As[cur];
    const char* pB = (const char*)Bs[cur];
#pragma unroll
    for (int ks = 0; ks < 2; ++ks) {
      bf16x8 af[4], bfr[4];
#pragma unroll
      for (int mi = 0; mi < 4; ++mi) {
        const int row = wm * 64 + mi * 16 + l15;
        const int slot = (ks * 4 + l4) ^ (row & 7);
        af[mi] = *(const bf16x8*)(pA + row * 128 + slot * 16);
      }
#pragma unroll
      for (int ni = 0; ni < 4; ++ni) {
        const int row = wn * 64 + ni * 16 + l15;
        const int slot = (ks * 4 + l4) ^ (row & 7);
        bfr[ni] = *(const bf16x8*)(pB + row * 128 + slot * 16);
      }
#pragma unroll
      for (int mi = 0; mi < 4; ++mi)
#pragma unroll
        for (int ni = 0; ni < 4; ++ni)
          acc[mi][ni] = MFMA16(af[mi], bfr[ni], acc[mi][ni]);
    }
    asm volatile("" ::: "memory");
    __builtin_amdgcn_s_barrier();
    cur ^= 1;
  }

#pragma unroll
  for (int mi = 0; mi < 4; ++mi) {
#pragma unroll
    for (int ni = 0; ni < 4; ++ni) {
      const int gm = m0 + wm * 64 + mi * 16 + l4 * 4;
      const int gn = n0 + wn * 64 + ni * 16 + l15;
      f32x4 v = acc[mi][ni];
#pragma unroll
      for (int r = 0; r < 4; ++r) {
        const size_t idx = (size_t)(gm + r) * N + gn;
        const float f = v[r];
        if constexpr (EPI == EPI_BF16) {
          ((ushort*)Cout)[idx] = f2bf(f * scale);
        } else if constexpr (EPI == EPI_RESID) {
          ((float*)Cout)[idx] = f + resid[idx];
        } else if constexpr (EPI == EPI_BIAS_GELU) {
          const float u = f + bias[gn];
          const float gl = 0.5f * u * (1.0f + erff(u * 0.70710678118654752f));
          ((ushort*)Cout)[idx] = f2bf(gl);
        } else if constexpr (EPI == EPI_BIAS_RESID) {
          ((float*)Cout)[idx] = f + bias[gn] + resid[idx];
        }
      }
    }
  }
}

// ------------- merged QKV GEMM: N=2304, segment epilogue, 2-phase -------------
__global__ __launch_bounds__(256) void gemm_qkv(
    const ushort* __restrict__ A, const ushort* __restrict__ Bt,
    ushort* __restrict__ qout, ushort* __restrict__ kout, ushort* __restrict__ vtout,
    int M, int K, float qscale) {
  __shared__ ushort As[2][128 * 64];
  __shared__ ushort Bs[2][128 * 64];
  const int tid = threadIdx.x;
  const int lane = tid & 63, wid = tid >> 6;
  const int wm = wid >> 1, wn = wid & 1;
  const int l15 = lane & 15, l4 = lane >> 4;
  const int m0 = blockIdx.y * 128, n0 = blockIdx.x * 128;
  const int srow = lane >> 3, sslot = lane & 7;
  const int skel = (sslot ^ srow) << 3;

  f32x4 acc[4][4] = {};

#pragma unroll
  for (int i = 0; i < 4; ++i) {
    const int c = i * 4 + wid;
    const int row = c * 8 + srow;
    gload16(A + (size_t)(m0 + row) * K + skel, (char*)As[0] + c * 1024);
    gload16(Bt + (size_t)(n0 + row) * K + skel, (char*)Bs[0] + c * 1024);
  }

  int cur = 0;
  for (int k0 = 0; k0 < K; k0 += 64) {
    if (k0 + 64 < K) {
      char* dA = (char*)As[cur ^ 1];
      char* dB = (char*)Bs[cur ^ 1];
#pragma unroll
      for (int i = 0; i < 4; ++i) {
        const int c = i * 4 + wid;
        const int row = c * 8 + srow;
        gload16(A + (size_t)(m0 + row) * K + k0 + 64 + skel, dA + c * 1024);
        gload16(Bt + (size_t)(n0 + row) * K + k0 + 64 + skel, dB + c * 1024);
      }
      asm volatile("s_waitcnt vmcnt(8)" ::: "memory");
    } else {
      asm volatile("s_waitcnt vmcnt(0)" ::: "memory");
    }
    __builtin_amdgcn_s_barrier();

    const char* pA = (const char*)As[cur];
    const char* pB = (const char*)Bs[cur];
#pragma unroll
    for (int ks = 0; ks < 2; ++ks) {
      bf16x8 af[4], bfr[4];
#pragma unroll
      for (int mi = 0; mi < 4; ++mi) {
        const int row = wm * 64 + mi * 16 + l15;
        const int slot = (ks * 4 + l4) ^ (row & 7);
        af[mi] = *(const bf16x8*)(pA + row * 128 + slot * 16);
      }
#pragma unroll
      for (int ni = 0; ni < 4; ++ni) {
        const int row = wn * 64 + ni * 16 + l15;
        const int slot = (ks * 4 + l4) ^ (row & 7);
        bfr[ni] = *(const bf16x8*)(pB + row * 128 + slot * 16);
      }
#pragma unroll
      for (int mi = 0; mi < 4; ++mi)
#pragma unroll
        for (int ni = 0; ni < 4; ++ni)
          acc[mi][ni] = MFMA16(af[mi], bfr[ni], acc[mi][ni]);
    }
    asm volatile("" ::: "memory");
    __builtin_amdgcn_s_barrier();
    cur ^= 1;
  }

  const int seg = n0 / 768;  // uniform per block (768 % 128 == 0)
#pragma unroll
  for (int mi = 0; mi < 4; ++mi) {
#pragma unroll
    for (int ni = 0; ni < 4; ++ni) {
      const int gm = m0 + wm * 64 + mi * 16 + l4 * 4;
      const int gn = n0 + wn * 64 + ni * 16 + l15;
      const int col = gn - seg * 768;
      f32x4 v = acc[mi][ni];
      if (seg == 0) {
#pragma unroll
        for (int r = 0; r < 4; ++r)
          qout[(size_t)(gm + r) * 768 + col] = f2bf(v[r] * qscale);
      } else if (seg == 1) {
#pragma unroll
        for (int r = 0; r < 4; ++r)
          kout[(size_t)(gm + r) * 768 + col] = f2bf(v[r]);
      } else {
        const int b = gm >> 12, tt = gm & 4095;
        const int h = col >> 6, dh = col & 63;
        ushort4 pk;
        pk.x = f2bf(v[0]); pk.y = f2bf(v[1]); pk.z = f2bf(v[2]); pk.w = f2bf(v[3]);
        *(ushort4*)(vtout + (((size_t)(b * 12 + h) * 64 + dh) * 4096 + tt)) = pk;
      }
    }
  }
}

// -------- causal MFMA flash attention, split-K x2 (balance the triangle) ------
// Each (bh,qb) pair -> 2 blocks: half 0 = key-tiles [0,nt/2), half 1 = [nt/2,nt)
// (half 1 owns the diagonal). Static max => additive merge. Partials written
// unnormalized (bf16) + fp32 denominators; attn_merge normalizes.
__global__ __launch_bounds__(256, 5) void flash_attn_kernel(
    const ushort* __restrict__ Q, const ushort* __restrict__ Kb,
    const ushort* __restrict__ Vt, ushort* __restrict__ Opart,
    float* __restrict__ dsb) {
  __shared__ ushort Ks[2][64 * 64];   // [key][kd], 8-slot XOR swizzle
  __shared__ ushort Vts[2][64 * 64];  // [dh][key], 8-slot XOR swizzle
  const int tid = threadIdx.x, lane = tid & 63, wid = tid >> 6;
  const int l15 = lane & 15, l4 = lane >> 4;
  const int l7 = l15 & 7;
  const int bid = (int)blockIdx.x;
  const int idx = (bid & 7) * 384 + (bid >> 3);
  const int pair = idx >> 1, half = idx & 1;
  const int bh = pair >> 6, b = bh / 12, h = bh % 12;
  const int qb = 63 - (pair & 63);
  const int qbase = qb * 64;
  const int q0 = qbase + wid * 16;
  const int nt = qb + 1;
  const int h0 = nt >> 1;
  const int kt0 = half ? h0 : 0;
  const int kt1 = half ? nt : h0;

  bf16x8 qf0, qf1;
  {
    const ushort* qp = Q + ((size_t)(b * 4096 + q0 + l15) * 768 + h * 64 + l4 * 8);
    qf0 = *(const bf16x8*)qp;
    qf1 = *(const bf16x8*)(qp + 32);
  }
  f32x4 oo[4] = {};
  float dsum = 0.f;

  const int srow_l = lane >> 3;
  const int sco = ((lane & 7) ^ srow_l) << 3;
  const ushort* Kbase = Kb + (size_t)b * 4096 * 768 + h * 64;
  const ushort* Vbase = Vt + (size_t)bh * 64 * 4096;
  const int c0 = wid, c1 = 4 + wid;
  const ushort* kp0 = Kbase + (size_t)(kt0 * 64 + c0 * 8 + srow_l) * 768 + sco;
  const ushort* kp1 = Kbase + (size_t)(kt0 * 64 + c1 * 8 + srow_l) * 768 + sco;
  const ushort* vp0 = Vbase + (size_t)(c0 * 8 + srow_l) * 4096 + kt0 * 64 + sco;
  const ushort* vp1 = Vbase + (size_t)(c1 * 8 + srow_l) * 4096 + kt0 * 64 + sco;

  const int koff0 = l15 * 128 + ((l4 ^ l7) << 4);
  const int koff1 = l15 * 128 + (((4 + l4) ^ l7) << 4);
  const int vbase_off = l15 * 128 + ((l4 & 1) << 3);
  const int t2b = l4 >> 1;
  // hoisted per-ct V swizzle offsets (ct is unroll-constant -> folds to regs)
  const int xoa[4] = {((0 + t2b) ^ l7) << 4, ((2 + t2b) ^ l7) << 4,
                      ((4 + t2b) ^ l7) << 4, ((6 + t2b) ^ l7) << 4};

  if (kt0 < kt1) {
    gload16(kp0, (char*)Ks + c0 * 1024);
    gload16(kp1, (char*)Ks + c1 * 1024);
    gload16(vp0, (char*)Vts + c0 * 1024);
    gload16(vp1, (char*)Vts + c1 * 1024);
  }

  int cur = 0;
  for (int kt = kt0; kt < kt1; ++kt) {
    const int k0 = kt << 6;
    if (kt + 1 < kt1) {
      kp0 += 64 * 768; kp1 += 64 * 768;
      vp0 += 64; vp1 += 64;
      const int nb = (cur ^ 1) * 8192;
      gload16(kp0, (char*)Ks + nb + c0 * 1024);
      gload16(kp1, (char*)Ks + nb + c1 * 1024);
      gload16(vp0, (char*)Vts + nb + c0 * 1024);
      gload16(vp1, (char*)Vts + nb + c1 * 1024);
      asm volatile("s_waitcnt vmcnt(4)" ::: "memory");
    } else {
      asm volatile("s_waitcnt vmcnt(0)" ::: "memory");
    }
    __builtin_amdgcn_s_barrier();

    const int nf = (q0 + 16 - k0) >> 4;
    const int nct = nf < 4 ? nf : 4;
    const bool has_diag = (nf <= 4);
    const char* Kc = (const char*)Ks + cur * 8192;
    const char* Vb = (const char*)Vts + cur * 8192 + vbase_off;

    __builtin_amdgcn_s_setprio(1);
#pragma unroll
    for (int ct = 0; ct < 4; ++ct) {
      if (ct < nct) {
        f32x4 s = {0.f, 0.f, 0.f, 0.f};
        const bf16x8 kf0 = *(const bf16x8*)(Kc + ct * 2048 + koff0);
        const bf16x8 kf1 = *(const bf16x8*)(Kc + ct * 2048 + koff1);
        s = MFMA16(kf0, qf0, s);
        s = MFMA16(kf1, qf1, s);
        if (has_diag && ct == nct - 1) {
#pragma unroll
          for (int r = 0; r < 4; ++r)
            if (l4 * 4 + r > l15) s[r] = -30.f;
        }
        const float p0 = __builtin_amdgcn_exp2f(s[0]);
        const float p1 = __builtin_amdgcn_exp2f(s[1]);
        const float p2 = __builtin_amdgcn_exp2f(s[2]);
        const float p3 = __builtin_amdgcn_exp2f(s[3]);
        dsum += (p0 + p1) + (p2 + p3);
        union { bf16x4 v; ushort u[4]; } pk;
        pk.u[0] = f2bf(p0); pk.u[1] = f2bf(p1);
        pk.u[2] = f2bf(p2); pk.u[3] = f2bf(p3);
        const char* Vp = Vb + xoa[ct];
#pragma unroll
        for (int dt = 0; dt < 4; ++dt) {
          const bf16x4 vf = *(const bf16x4*)(Vp + dt * 2048);
          oo[dt] = mfma_k16(pk.v, vf, oo[dt]);
        }
      }
    }
    __builtin_amdgcn_s_setprio(0);
    asm volatile("" ::: "memory");
    __builtin_amdgcn_s_barrier();
    cur ^= 1;
  }

  dsum += __shfl_xor(dsum, 16);
  dsum += __shfl_xor(dsum, 32);
  if (l4 == 0)
    dsb[((half * 24 + b * 12 + h) << 12) + q0 + l15] = dsum;
  ushort* op = Opart + ((size_t)(half * 8192 + b * 4096 + q0 + l4 * 4)) * 768 + h * 64;
#pragma unroll
  for (int r = 0; r < 4; ++r) {
#pragma unroll
    for (int dt = 0; dt < 4; ++dt)
      op[(size_t)r * 768 + dt * 16 + l15] = f2bf(oo[dt][r]);
  }
}

// ---------------- merge split-K partials: attn = (P0+P1)/(d0+d1) -------------
__global__ void attn_merge(const ushort* __restrict__ P, const float* __restrict__ ds,
                           ushort* __restrict__ attn) {
  const int row = blockIdx.x, t = threadIdx.x;
  const int b = row >> 12, tr = row & 4095;
  __shared__ float inv[12];
  if (t < 12) {
    const float d0 = ds[((b * 12 + t) << 12) + tr];
    const float d1 = ds[((24 + b * 12 + t) << 12) + tr];
    inv[t] = 1.0f / (d0 + d1);
  }
  __syncthreads();
  const size_t o0 = (size_t)row * 768 + 4 * t;
  const ushort4 a = *(const ushort4*)(P + o0);
  const ushort4 c = *(const ushort4*)(P + (size_t)8192 * 768 + o0);
  const float iv = inv[t >> 4];
  ushort4 o;
  o.x = f2bf((bf2f(a.x) + bf2f(c.x)) * iv);
  o.y = f2bf((bf2f(a.y) + bf2f(c.y)) * iv);
  o.z = f2bf((bf2f(a.z) + bf2f(c.z)) * iv);
  o.w = f2bf((bf2f(a.w) + bf2f(c.w)) * iv);
  *(ushort4*)(attn + o0) = o;
}

extern "C" void kernel_launch(void* const* d_in, const int* in_sizes, int n_in,
                              void* d_out, int out_size, void* d_ws, size_t ws_size,
                              hipStream_t stream) {
  const float* x  = (const float*)d_in[0];
  const float* wq = (const float*)d_in[1];
  const float* wk = (const float*)d_in[2];
  const float* wv = (const float*)d_in[3];
  const float* wo = (const float*)d_in[4];
  const float* w1 = (const float*)d_in[5];
  const float* b1 = (const float*)d_in[6];
  const float* w2 = (const float*)d_in[7];
  const float* b2 = (const float*)d_in[8];
  const float* g1 = (const float*)d_in[9];
  const float* g2 = (const float*)d_in[10];
  float* out = (float*)d_out;

  char* p = (char*)d_ws;
  ushort* wqT = (ushort*)p; p += (size_t)768 * 768 * 2;   // } contiguous: one
  ushort* wkT = (ushort*)p; p += (size_t)768 * 768 * 2;   // } 2304x768 B matrix
  ushort* wvT = (ushort*)p; p += (size_t)768 * 768 * 2;   // } for merged QKV
  ushort* woT = (ushort*)p; p += (size_t)768 * 768 * 2;
  ushort* w1T = (ushort*)p; p += (size_t)3072 * 768 * 2;
  ushort* w2T = (ushort*)p; p += (size_t)768 * 3072 * 2;
  ushort* xn  = (ushort*)p; p += (size_t)8192 * 768 * 2;
  ushort* qb  = (ushort*)p; p += (size_t)8192 * 768 * 2;
  ushort* kb  = (ushort*)p; p += (size_t)8192 * 768 * 2;
  ushort* vtb = (ushort*)p; p += (size_t)8192 * 768 * 2;
  ushort* attn = (ushort*)p; p += (size_t)8192 * 768 * 2;
  float* x2 = (float*)p; p += (size_t)8192 * 768 * 4;
  float* dsb = (float*)p; p += (size_t)2 * 24 * 4096 * 4;
  ushort* hf = qb;              // reuse qb..attn region (8192*3072*2 bytes)
  ushort* Opart = (ushort*)x2;  // x2 region free until WO GEMM

  const float qscale = 0.125f * 1.44269504088896340736f;

  dim3 blk(256);
  wtrans_all<<<dim3(6912), blk, 0, stream>>>(wq, wk, wv, wo, w1, w2,
                                             wqT, wkT, wvT, woT, w1T, w2T);

  rmsnorm_kernel<<<8192, dim3(192), 0, stream>>>(x, g1, xn);

  gemm_qkv<<<dim3(18, 64), blk, 0, stream>>>(xn, wqT, qb, kb, vtb, 8192, 768, qscale);

  flash_attn_kernel<<<dim3(3072), blk, 0, stream>>>(qb, kb, vtb, Opart, dsb);

  attn_merge<<<dim3(8192), dim3(192), 0, stream>>>(Opart, dsb, attn);

  gemm_bt<EPI_RESID><<<dim3(6, 64), blk, 0, stream>>>(attn, woT, x2, nullptr, x, 8192, 768, 768, 1.0f);

  rmsnorm_kernel<<<8192, dim3(192), 0, stream>>>(x2, g2, xn);

  gemm_bt<EPI_BIAS_GELU><<<dim3(24, 64), blk, 0, stream>>>(xn, w1T, hf, b1, nullptr, 8192, 3072, 768, 1.0f);

  gemm_bt<EPI_BIAS_RESID><<<dim3(6, 64), blk, 0, stream>>>(hf, w2T, out, b2, x2, 8192, 768, 3072, 1.0f);
}